// Round 9
// baseline (259.380 us; speedup 1.0000x reference)
//
#include <hip/hip_runtime.h>
#include <hip/hip_bf16.h>
#include <math.h>

typedef unsigned short ushort_t;
typedef __attribute__((ext_vector_type(8))) __bf16 bf16x8;
typedef __attribute__((ext_vector_type(4))) float f32x4;
typedef __attribute__((ext_vector_type(16))) float f32x16;
typedef __attribute__((ext_vector_type(4))) unsigned int u32x4;

#define E_DIM 512
#define HEADS 8
#define HD 64
#define SEQ 2048
#define NROWS 8192        // B * SEQ
#define QSCALE 0.18033688011112042f   // 0.125 * log2(e): scores in log2 domain

static __device__ __forceinline__ unsigned short f2b(float f) {
  unsigned int x;
  __builtin_memcpy(&x, &f, 4);
  x += 0x7fffu + ((x >> 16) & 1u);   // RNE (cold epilogues only)
  return (unsigned short)(x >> 16);
}

// v_cvt_pk_bf16_f32: pack 2 f32 -> 2 bf16 (RNE) in one u32. No builtin on gfx950.
static __device__ __forceinline__ unsigned cvt_pk_bf16(float lo, float hi) {
  unsigned r;
  asm("v_cvt_pk_bf16_f32 %0, %1, %2" : "=v"(r) : "v"(lo), "v"(hi));
  return r;
}

// raw v_exp_f32 (2^x): skips ocml's subnormal-fixup sequence.
static __device__ __forceinline__ float fexp2(float x) {
  float r;
  asm("v_exp_f32 %0, %1" : "=v"(r) : "v"(x));
  return r;
}

// sign-extended 1-bit field extract: 0 or 0xFFFFFFFF (v_bfe_i32, 1 inst)
static __device__ __forceinline__ unsigned bitmask1(unsigned v, int off) {
#if __has_builtin(__builtin_amdgcn_sbfe)
  return (unsigned)__builtin_amdgcn_sbfe((int)v, off, 1);
#else
  return (unsigned)((int)(v << (31 - off)) >> 31);
#endif
}

// XOR-swizzled LDS index for 64-col bf16 tiles (16B chunks) — conflict-free reads.
static __device__ __forceinline__ int swz(int row, int col) {
  return row * 64 + ((((col >> 3) ^ (row & 7)) & 7) << 3) + (col & 7);
}

// Async 16B/lane global->LDS DMA; dest = lds_base + lane*16B (wave-uniform base).
// Caller realizes the swizzle by permuting the per-lane GLOBAL address.
// NOTE (R5 lesson): this staging is the COALESCING engine — MFMA fragments make lane l
// read row (l&31) (1-4KB strides, 64 lines/wave if direct-global); DMA reads contiguous
// 1KB then the scattered access hits conflict-free LDS. Direct-global K/V loads = 2.4x slower.
static __device__ __forceinline__ void gl2lds16(const ushort_t* g, ushort_t* s) {
#if __has_builtin(__builtin_amdgcn_global_load_lds)
  __builtin_amdgcn_global_load_lds(
      (const __attribute__((address_space(1))) unsigned int*)(uintptr_t)g,
      (__attribute__((address_space(3))) unsigned int*)(uintptr_t)s,
      16, 0, 0);
#else
  int l = threadIdx.x & 63;
  *(u32x4*)(s + l * 8) = *(const u32x4*)g;
#endif
}

// ---------------- prep: fused transposeW(x4) + 2x LayerNorm ----------------
// (mask-pack moved into proj3's grid for compute/memory overlap — R9)
__launch_bounds__(256)
__global__ void prep_kernel(const float* __restrict__ Wq, const float* __restrict__ Wk,
                            const float* __restrict__ Wv, const float* __restrict__ Wo,
                            ushort_t* __restrict__ WT,
                            const float* __restrict__ xq, const float* __restrict__ xkv,
                            const float* __restrict__ gq, const float* __restrict__ bq,
                            const float* __restrict__ gkv, const float* __restrict__ bkv,
                            ushort_t* __restrict__ yq, ushort_t* __restrict__ ykv) {
  int blk = blockIdx.x;
  int t = threadIdx.x;
  if (blk < 1024) {                       // ---- weight transpose+cast
    int z = blk >> 8, rem = blk & 255;
    const float* in = (z == 0) ? Wq : (z == 1) ? Wk : (z == 2) ? Wv : Wo;
    ushort_t* o = WT + (size_t)z * E_DIM * E_DIM;
    __shared__ float tile[32 * 33];
    int tx = t & 31, ty = t >> 5;
    int n0 = (rem & 15) * 32, k0 = (rem >> 4) * 32;
#pragma unroll
    for (int i = 0; i < 4; ++i) {
      int k = ty + i * 8;
      tile[k * 33 + tx] = in[(k0 + k) * E_DIM + n0 + tx];
    }
    __syncthreads();
#pragma unroll
    for (int i = 0; i < 4; ++i) {
      int n = ty + i * 8;
      o[(n0 + n) * E_DIM + k0 + tx] = f2b(tile[tx * 33 + n]);
    }
  } else {                                // ---- LayerNorm, both tensors
    int idx = blk - 1024;
    int which = idx >> 11;
    const float* x = which ? xkv : xq;
    const float* g = which ? gkv : gq;
    const float* bb = which ? bkv : bq;
    ushort_t* y = which ? ykv : yq;
    int w = t >> 6, l = t & 63;
    int row = (idx & 2047) * 4 + w;
    f32x4 x0 = *(const f32x4*)&x[row * E_DIM + l * 8];
    f32x4 x1 = *(const f32x4*)&x[row * E_DIM + l * 8 + 4];
    float xf[8], s = 0.f, ss = 0.f;
#pragma unroll
    for (int j = 0; j < 8; ++j) {
      xf[j] = (j < 4) ? x0[j] : x1[j - 4];
      s += xf[j];
      ss += xf[j] * xf[j];
    }
#pragma unroll
    for (int off = 32; off > 0; off >>= 1) {
      s += __shfl_xor(s, off);
      ss += __shfl_xor(ss, off);
    }
    float mu = s * (1.f / 512.f);
    float var = fmaxf(ss * (1.f / 512.f) - mu * mu, 0.f);
    float rs = rsqrtf(var + 1e-5f);
    f32x4 g0 = *(const f32x4*)&g[l * 8];
    f32x4 g1 = *(const f32x4*)&g[l * 8 + 4];
    f32x4 b0 = *(const f32x4*)&bb[l * 8];
    f32x4 b1 = *(const f32x4*)&bb[l * 8 + 4];
#pragma unroll
    for (int j = 0; j < 8; ++j) {
      float gv = (j < 4) ? g0[j] : g1[j - 4];
      float bv = (j < 4) ? b0[j] : b1[j - 4];
      y[row * E_DIM + l * 8 + j] = f2b((xf[j] - mu) * rs * gv + bv);
    }
  }
}

// ------------- GEMM core, 128x64 tile, BK=64, 4 waves in 2x2 (each 64x32) -------------
// (R3 config — best measured non-attn schedule.)
// MODE 0: bf16 row-major C (with scale)  MODE 1: fp32 row-major C
// MODE 2: bf16 Vt-transposed epilogue  Vt[((b*8+h)*64+d)*2048 + k]  (packed uint2 along k)
template <int MODE>
static __device__ __forceinline__ void gemm_core64(ushort_t* lA, ushort_t* lB,
                                                   const ushort_t* __restrict__ A,
                                                   const ushort_t* __restrict__ WT,
                                                   const float* __restrict__ bias,
                                                   void* Cv, float scale, int m0, int n0) {
  int t = threadIdx.x, w = t >> 6, l = t & 63;
  int quad = l >> 4, l15 = l & 15;
  int wm_ = w >> 1, wn_ = w & 1;
  int csrc = ((l & 7) ^ (l >> 3)) * 8;   // swizzle folded into per-lane global column
  int rln = l >> 3;

  f32x4 acc[4][2] = {};
  for (int kk = 0; kk < E_DIM; kk += 64) {
    __syncthreads();
#pragma unroll
    for (int i = 0; i < 4; ++i) {        // A: 128 rows
      int r0 = i * 32 + w * 8;
      gl2lds16(&A[(size_t)(m0 + r0 + rln) * E_DIM + kk + csrc], &lA[r0 * 64]);
    }
#pragma unroll
    for (int i = 0; i < 2; ++i) {        // B: 64 rows
      int r0 = i * 32 + w * 8;
      gl2lds16(&WT[(size_t)(n0 + r0 + rln) * E_DIM + kk + csrc], &lB[r0 * 64]);
    }
    __syncthreads();
#pragma unroll
    for (int ks = 0; ks < 2; ++ks) {
      bf16x8 af[4], bf[2];
#pragma unroll
      for (int mt = 0; mt < 4; ++mt)
        af[mt] = *(const bf16x8*)&lA[swz(wm_ * 64 + mt * 16 + l15, ks * 32 + quad * 8)];
#pragma unroll
      for (int nt = 0; nt < 2; ++nt)
        bf[nt] = *(const bf16x8*)&lB[swz(wn_ * 32 + nt * 16 + l15, ks * 32 + quad * 8)];
#pragma unroll
      for (int mt = 0; mt < 4; ++mt)
#pragma unroll
        for (int nt = 0; nt < 2; ++nt)
          acc[mt][nt] = __builtin_amdgcn_mfma_f32_16x16x32_bf16(af[mt], bf[nt], acc[mt][nt], 0, 0, 0);
    }
  }

#pragma unroll
  for (int nt = 0; nt < 2; ++nt) {
    int col = n0 + wn_ * 32 + nt * 16 + l15;
    float bv = bias[col];
    if constexpr (MODE == 2) {
      int h = col >> 6, d = col & 63;
#pragma unroll
      for (int mt = 0; mt < 4; ++mt) {
        int row = m0 + wm_ * 64 + mt * 16 + quad * 4;   // 4 consecutive k (r=0..3)
        int b = row >> 11, k = row & 2047;
        union { ushort_t u[4]; uint2 v; } pk;
#pragma unroll
        for (int r = 0; r < 4; ++r) pk.u[r] = f2b(acc[mt][nt][r] + bv);
        *(uint2*)&((ushort_t*)Cv)[((((size_t)(b * HEADS + h)) * HD + d) << 11) + k] = pk.v;
      }
    } else {
#pragma unroll
      for (int mt = 0; mt < 4; ++mt) {
#pragma unroll
        for (int r = 0; r < 4; ++r) {
          int rowm = m0 + wm_ * 64 + mt * 16 + quad * 4 + r;   // C/D: col=l&15, row=quad*4+r
          float val = (acc[mt][nt][r] + bv) * scale;
          if constexpr (MODE == 0)
            ((ushort_t*)Cv)[rowm * E_DIM + col] = f2b(val);
          else
            ((float*)Cv)[rowm * E_DIM + col] = val;
        }
      }
    }
  }
}

// Fused projections + INTERLEAVED mask-pack (R9): grid = groups*(nm+ng). Per group of
// (nm mask blocks + ng gemm blocks) — memory-bound mask packing co-resident with
// compute-bound GEMM on every CU (overlap instead of the old serial prep phase).
// Mask bit order (producer+consumer agree): within each 64-k word, bit p holds
// k_local = 4*(p&15) + (p>>4). GEMM: z = zbase + work/512:
//   0: qp=(qn@WTq+bq)*QSCALE   1: Vt=T(kvn@WTv+bv)   2: kp=kvn@WTk+bk
__launch_bounds__(256)
__global__ void proj3_kernel(const ushort_t* __restrict__ qn, const ushort_t* __restrict__ WTq,
                             const float* __restrict__ bq, ushort_t* __restrict__ qp,
                             const ushort_t* __restrict__ kvn, const ushort_t* __restrict__ WTv,
                             const float* __restrict__ bv, ushort_t* __restrict__ Vt,
                             const ushort_t* __restrict__ WTk, const float* __restrict__ bk,
                             ushort_t* __restrict__ kp,
                             const int* __restrict__ kvm, const int* __restrict__ sp,
                             unsigned long long* __restrict__ bits,
                             int nm, int ng, int ngemm, int zbase) {
  __shared__ ushort_t lA[128 * 64];
  __shared__ ushort_t lB[64 * 64];
  int flat = blockIdx.x;
  int gsz = nm + ng;
  int grp = flat / gsz, r = flat % gsz;
  if (r < nm) {                           // ---- mask pack block (int4-vectorized, ballot)
    int mb = grp * nm + r;                // [0, 2048) -> 4 rows each
    int w = threadIdx.x >> 6, l = threadIdx.x & 63;
    int row = mb * 4 + w;
    int b = row >> 11;
    const int4* sprow = (const int4*)(sp + ((size_t)row << 11));
    const int4* kvrow = (const int4*)(kvm + ((size_t)b << 11));
    unsigned long long* out = bits + ((size_t)row << 5);
#pragma unroll
    for (int it = 0; it < 8; ++it) {
      int4 s4 = sprow[it * 64 + l];
      int4 k4 = kvrow[it * 64 + l];
      unsigned nib = (unsigned)((s4.x && k4.x) ? 1 : 0) | ((s4.y && k4.y) ? 2u : 0)
                   | ((s4.z && k4.z) ? 4u : 0) | ((s4.w && k4.w) ? 8u : 0);
      unsigned long long b0 = __ballot((nib & 1u) != 0);
      unsigned long long b1 = __ballot((nib & 2u) != 0);
      unsigned long long b2 = __ballot((nib & 4u) != 0);
      unsigned long long b3 = __ballot((nib & 8u) != 0);
      if (l < 4) {
        int m16 = l * 16;
        unsigned long long wv = ((b0 >> m16) & 0xFFFFull)
                              | (((b1 >> m16) & 0xFFFFull) << 16)
                              | (((b2 >> m16) & 0xFFFFull) << 32)
                              | (((b3 >> m16) & 0xFFFFull) << 48);
        out[it * 4 + l] = wv;
      }
    }
    return;
  }
  int gid = grp * ng + (r - nm);          // [0, ngemm)
  int chunk = ngemm >> 3;
  int work = (gid & 7) * chunk + (gid >> 3);   // bijective id-space swizzle
  int z = zbase + (work >> 9);
  int rr = work & 511;
  int m0 = (rr >> 3) * 128, n0 = (rr & 7) * 64;
  if (z == 0)      gemm_core64<0>(lA, lB, qn,  WTq, bq, qp, QSCALE, m0, n0);
  else if (z == 1) gemm_core64<2>(lA, lB, kvn, WTv, bv, Vt, 1.f,    m0, n0);
  else             gemm_core64<0>(lA, lB, kvn, WTk, bk, kp, 1.f,    m0, n0);
}

// Output GEMM: ctx@WTo+bo -> fp32. 512 blocks (2/CU), XCD-chunked.
__launch_bounds__(256)
__global__ void out_kernel(const ushort_t* __restrict__ A, const ushort_t* __restrict__ WT,
                           const float* __restrict__ bias, float* __restrict__ C) {
  __shared__ ushort_t lA[128 * 64];
  __shared__ ushort_t lB[64 * 64];
  int flat = blockIdx.x;
  int work = (flat & 7) * 64 + (flat >> 3);
  int m0 = (work >> 3) * 128, n0 = (work & 7) * 64;
  gemm_core64<1>(lA, lB, A, WT, bias, C, 1.f, m0, n0);
}

// softmax + in-register P->B-fragment build for one 64-k tile (two 32x32 halves).
// Mask bit order: element (kt2,half,g,r) -> bit (8*kt2+2*g+half)+16*(r&1) of (r<2?lo:hi).
static __device__ __forceinline__ void softmax_frag(const f32x16& s0, const f32x16& s1,
                                                    unsigned mlo, unsigned mhi, int half,
                                                    bf16x8* pf, f32x16* dummy_unused) {
#pragma unroll
  for (int kt2 = 0; kt2 < 2; ++kt2) {
    const f32x16& sv = kt2 ? s1 : s0;
    unsigned wa[4], wb[4];
#pragma unroll
    for (int g = 0; g < 4; ++g) {
      int bb = 8 * kt2 + 2 * g + half;
      unsigned q0u = __float_as_uint(fexp2(sv[g * 4 + 0])) & bitmask1(mlo, bb);
      unsigned q1u = __float_as_uint(fexp2(sv[g * 4 + 1])) & bitmask1(mlo, bb + 16);
      unsigned q2u = __float_as_uint(fexp2(sv[g * 4 + 2])) & bitmask1(mhi, bb);
      unsigned q3u = __float_as_uint(fexp2(sv[g * 4 + 3])) & bitmask1(mhi, bb + 16);
      wa[g] = cvt_pk_bf16(__uint_as_float(q0u), __uint_as_float(q1u));
      wb[g] = cvt_pk_bf16(__uint_as_float(q2u), __uint_as_float(q3u));
    }
    asm("v_permlane32_swap_b32 %0, %1" : "+v"(wa[0]), "+v"(wa[1]));
    asm("v_permlane32_swap_b32 %0, %1" : "+v"(wb[0]), "+v"(wb[1]));
    asm("v_permlane32_swap_b32 %0, %1" : "+v"(wa[2]), "+v"(wa[3]));
    asm("v_permlane32_swap_b32 %0, %1" : "+v"(wb[2]), "+v"(wb[3]));
    union { unsigned u[4]; bf16x8 v; } f0, f1;
    f0.u[0] = wa[0]; f0.u[1] = wb[0]; f0.u[2] = wa[1]; f0.u[3] = wb[1];
    f1.u[0] = wa[2]; f1.u[1] = wb[2]; f1.u[2] = wa[3]; f1.u[3] = wb[3];
    pf[kt2 * 2 + 0] = f0.v;
    pf[kt2 * 2 + 1] = f1.v;
  }
}

// ---------------- flash attention: 2-tile ILP build (R8 — best measured, CONTROL) ----------
// ILP-NOT-OCCUPANCY: R1/R6/R7 proved occupancy is register-capped (~2-3 waves/SIMD, unified
// VGPR+AGPR); latency-hiding comes from TWO independent k-tiles (A,B) per iteration —
// QK/SM/PV chains interleave, barriers per tile halve. 256 threads = (2 q-waves) x
// (2 k-slices); slice ks handles kt = 4*t8 + 2*ks + {0,1}. Partials additive (no-max log2
// softmax) -> 2-way LDS merge. LDS 72KB. XCD-bijective swizzle keeps (b,h) K/V on one XCD L2.
// LDS staging kept: it is the coalescing engine (R5: direct-global = 2.4x slower).
__launch_bounds__(256)
__global__ void attn_kernel(const ushort_t* __restrict__ Qp, const ushort_t* __restrict__ Kp,
                            const ushort_t* __restrict__ Vt,
                            const unsigned long long* __restrict__ bits,
                            ushort_t* __restrict__ ctx) {
  __shared__ __align__(16) char smemb[73728];
  ushort_t* sQ = (ushort_t*)smemb;                        // [0, 8192) — never reused in loop
  int t = threadIdx.x, w = t >> 6, l = t & 63;
  int qw = w & 1, ks = w >> 1;                            // ks in {0,1}
  ushort_t* sKA = (ushort_t*)(smemb + 8192 + ks * 16384); // [8192, 40960)
  ushort_t* sKB = sKA + 4096;
  ushort_t* sVA = (ushort_t*)(smemb + 40960 + ks * 16384);// [40960, 73728)
  ushort_t* sVB = sVA + 4096;
  int l31 = l & 31, half = l >> 5;

  int flat = blockIdx.x;
  int work = (flat & 7) * 128 + (flat >> 3);   // bijective XCD chunking (1024 = 8*128)
  int qblk = work & 31;
  int h = (work >> 5) & 7;
  int b = work >> 8;
  int q0 = qblk * 64;
  int bh = b * HEADS + h;
  int myq = qw * 32 + l31;
  int csrc = ((l & 7) ^ (l >> 3)) * 8;
  int rln = l >> 3;

  // prologue: stage Q (64 rows, 8 DMAs across 4 waves), drain, read loop-invariant frags
#pragma unroll
  for (int it = 0; it < 2; ++it) {
    int r0 = w * 16 + it * 8;
    gl2lds16(&Qp[(size_t)(b * SEQ + q0 + r0 + rln) * E_DIM + h * HD + csrc], &sQ[r0 * 64]);
  }
  __syncthreads();
  bf16x8 qf[4];
#pragma unroll
  for (int ds = 0; ds < 4; ++ds)
    qf[ds] = *(const bf16x8*)&sQ[swz(myq, ds * 16 + 8 * half)];

  const unsigned long long* mrow = bits + ((size_t)(b * SEQ + q0 + myq) << 5);
  f32x16 o0 = {}, o1 = {}, lacc = {};
  union { unsigned u[4]; bf16x8 v; } onec;
#pragma unroll
  for (int i = 0; i < 4; ++i) onec.u[i] = 0x3f803f80u;   // bf16 1.0 pairs

  for (int t8 = 0; t8 < 8; ++t8) {
    int ktA = t8 * 4 + ks * 2;
    int kA0 = ktA * 64, kB0 = kA0 + 64;
    unsigned long long mA = mrow[ktA], mB = mrow[ktA + 1];
    __syncthreads();   // prev iteration's sK/sV reads done (both slices)
    // stage tiles A and B for this slice (2 waves x 16 DMAs)
#pragma unroll
    for (int it = 0; it < 4; ++it) {
      int r0 = (it * 2 + qw) * 8;
      gl2lds16(&Kp[(size_t)(b * SEQ + kA0 + r0 + rln) * E_DIM + h * HD + csrc], &sKA[r0 * 64]);
      gl2lds16(&Kp[(size_t)(b * SEQ + kB0 + r0 + rln) * E_DIM + h * HD + csrc], &sKB[r0 * 64]);
      gl2lds16(&Vt[((size_t)bh * HD + r0 + rln) * SEQ + kA0 + csrc], &sVA[r0 * 64]);
      gl2lds16(&Vt[((size_t)bh * HD + r0 + rln) * SEQ + kB0 + csrc], &sVB[r0 * 64]);
    }
    __syncthreads();   // DMA drained

    // QK^T for both tiles — independent chains, compiler interleaves
    f32x16 sA0 = {}, sA1 = {}, sB0 = {}, sB1 = {};
    __builtin_amdgcn_s_setprio(1);
#pragma unroll
    for (int ds = 0; ds < 4; ++ds) {
      bf16x8 kfA0 = *(const bf16x8*)&sKA[swz(l31, ds * 16 + 8 * half)];
      bf16x8 kfA1 = *(const bf16x8*)&sKA[swz(32 + l31, ds * 16 + 8 * half)];
      bf16x8 kfB0 = *(const bf16x8*)&sKB[swz(l31, ds * 16 + 8 * half)];
      bf16x8 kfB1 = *(const bf16x8*)&sKB[swz(32 + l31, ds * 16 + 8 * half)];
      sA0 = __builtin_amdgcn_mfma_f32_32x32x16_bf16(kfA0, qf[ds], sA0, 0, 0, 0);
      sA1 = __builtin_amdgcn_mfma_f32_32x32x16_bf16(kfA1, qf[ds], sA1, 0, 0, 0);
      sB0 = __builtin_amdgcn_mfma_f32_32x32x16_bf16(kfB0, qf[ds], sB0, 0, 0, 0);
      sB1 = __builtin_amdgcn_mfma_f32_32x32x16_bf16(kfB1, qf[ds], sB1, 0, 0, 0);
    }
    __builtin_amdgcn_s_setprio(0);

    // softmax for both tiles (independent VALU chains)
    bf16x8 pfA[4], pfB[4];
    softmax_frag(sA0, sA1, (unsigned)mA, (unsigned)(mA >> 32), half, pfA, nullptr);
    softmax_frag(sB0, sB1, (unsigned)mB, (unsigned)(mB >> 32), half, pfB, nullptr);

    // O^T += V^T P^T for both tiles ; lacc += 1^T P^T (row-sums on the MFMA pipe)
    __builtin_amdgcn_s_setprio(1);
#pragma unroll
    for (int ksp = 0; ksp < 4; ++ksp) {
      bf16x8 vfA0 = *(const bf16x8*)&sVA[swz(l31, ksp * 16 + 8 * half)];
      bf16x8 vfA1 = *(const bf16x8*)&sVA[swz(32 + l31, ksp * 16 + 8 * half)];
      o0 = __builtin_amdgcn_mfma_f32_32x32x16_bf16(vfA0, pfA[ksp], o0, 0, 0, 0);
      o1 = __builtin_amdgcn_mfma_f32_32x32x16_bf16(vfA1, pfA[ksp], o1, 0, 0, 0);
      lacc = __builtin_amdgcn_mfma_f32_32x32x16_bf16(onec.v, pfA[ksp], lacc, 0, 0, 0);
      bf16x8 vfB0 = *(const bf16x8*)&sVB[swz(l31, ksp * 16 + 8 * half)];
      bf16x8 vfB1 = *(const bf16x8*)&sVB[swz(32 + l31, ksp * 16 + 8 * half)];
      o0 = __builtin_amdgcn_mfma_f32_32x32x16_bf16(vfB0, pfB[ksp], o0, 0, 0, 0);
      o1 = __builtin_amdgcn_mfma_f32_32x32x16_bf16(vfB1, pfB[ksp], o1, 0, 0, 0);
      lacc = __builtin_amdgcn_mfma_f32_32x32x16_bf16(onec.v, pfB[ksp], lacc, 0, 0, 0);
    }
    __builtin_amdgcn_s_setprio(0);
  }

  // lacc[0] = full slice row-sum for q=lane&31 (identical in both halves)
  float lsum = lacc[0];

  // cross-slice merge: slice 1 writes partials to LDS (K area dead), slice 0 adds.
  __syncthreads();                       // all compute done before overwriting K area
  float* mrg = (float*)(smemb + 8192);   // [2 qw][64 lanes][33 floats] = 16.9KB
  if (ks == 1) {
    float* e = mrg + (qw * 64 + l) * 33;
#pragma unroll
    for (int r = 0; r < 16; ++r) e[r] = o0[r];
#pragma unroll
    for (int r = 0; r < 16; ++r) e[16 + r] = o1[r];
    e[32] = lsum;
  }
  __syncthreads();
  if (ks == 0) {
    const float* e = mrg + (qw * 64 + l) * 33;
#pragma unroll
    for (int r = 0; r < 16; ++r) o0[r] += e[r];
#pragma unroll
    for (int r = 0; r < 16; ++r) o1[r] += e[16 + r];
    lsum += e[32];
    float inv = (lsum > 0.f) ? 1.f / lsum : 0.f;   // all-masked row -> 0 (nan_to_num)
    size_t base = (size_t)(b * SEQ + q0 + myq) * E_DIM + h * HD;
#pragma unroll
    for (int dt = 0; dt < 2; ++dt) {
      const f32x16& oo = dt ? o1 : o0;
#pragma unroll
      for (int g = 0; g < 4; ++g) {
        union { ushort_t u[4]; uint2 v; } ov;
#pragma unroll
        for (int r = 0; r < 4; ++r) ov.u[r] = f2b(oo[g * 4 + r] * inv);
        *(uint2*)&ctx[base + dt * 32 + g * 8 + 4 * half] = ov.v;   // d=(r)+8g+4*half+32dt
      }
    }
  }
}

// ---------------- launch ----------------
// fp32 in/out, bf16 internals. d_out (16 MB fp32) = two 8 MB bf16 slots dlo/dhi.
// Preferred (ws >= 28 MiB): bufA(8) bufB(8) WT(2) bits(2) bufC(8):
//   1 prep:  WT, qn->dlo, kvn->bufA                       (5120 blocks)
//   2 proj3: qp->dhi, Vt->bufB, kp->bufC  ∥  mask->bits   (3584 = 512x{4 mask + 3 gemm})
//   3 attn:  (dhi, bufC, bufB, bits) -> bufA              (1024 x 256)
//   4 out:   bufA@WTo+bo -> d_out fp32                    (512)
// Fallback (ws < 28 MiB): proj3 split into (q,v ∥ mask) then (k->dlo).
extern "C" void kernel_launch(void* const* d_in, const int* in_sizes, int n_in,
                              void* d_out, int out_size, void* d_ws, size_t ws_size,
                              hipStream_t stream) {
  const float* query     = (const float*)d_in[0];
  const float* key_value = (const float*)d_in[1];
  const int*   kv_mask   = (const int*)d_in[2];
  const int*   sp_mask   = (const int*)d_in[3];
  const float* ln_q_g  = (const float*)d_in[4];
  const float* ln_q_b  = (const float*)d_in[5];
  const float* ln_kv_g = (const float*)d_in[6];
  const float* ln_kv_b = (const float*)d_in[7];
  const float* Wq = (const float*)d_in[8];
  const float* bq = (const float*)d_in[9];
  const float* Wk = (const float*)d_in[10];
  const float* bk = (const float*)d_in[11];
  const float* Wv = (const float*)d_in[12];
  const float* bv = (const float*)d_in[13];
  const float* Wo = (const float*)d_in[14];
  const float* bo = (const float*)d_in[15];

  const size_t NB = (size_t)NROWS * E_DIM;       // 8 MiB bf16 slot
  char* ws = (char*)d_ws;
  ushort_t* bufA = (ushort_t*)ws;                // kvn -> ctx
  ushort_t* bufB = bufA + NB;                    // Vt
  ushort_t* WT   = bufB + NB;                    // 4 x 512x512 bf16 = 2 MiB
  ushort_t* WTq = WT;
  ushort_t* WTk = WTq + E_DIM * E_DIM;
  ushort_t* WTv = WTk + E_DIM * E_DIM;
  ushort_t* WTo = WTv + E_DIM * E_DIM;
  unsigned long long* bits = (unsigned long long*)(WTo + E_DIM * E_DIM);  // 2 MiB
  ushort_t* bufC = (ushort_t*)(ws + (20u << 20));                         // kp (8 MiB)

  ushort_t* dlo = (ushort_t*)d_out;              // qn, then (fallback) kp
  ushort_t* dhi = dlo + NB;                      // qp

  bool fused = ws_size >= (28u << 20);
  ushort_t* kp = fused ? bufC : dlo;

  prep_kernel<<<5120, 256, 0, stream>>>(Wq, Wk, Wv, Wo, WT,
                                        query, key_value, ln_q_g, ln_q_b, ln_kv_g, ln_kv_b,
                                        dlo, bufA);

  if (fused) {
    // 512 groups x (4 mask + 3 gemm) = 3584 blocks; gemm ids [0,1536) -> z in {0,1,2}
    proj3_kernel<<<3584, 256, 0, stream>>>(dlo, WTq, bq, dhi,
                                           bufA, WTv, bv, bufB,
                                           WTk, bk, bufC,
                                           kv_mask, sp_mask, bits,
                                           4, 3, 1536, 0);
  } else {
    // 1024 groups x (2 mask + 1 gemm) = 3072; gemm ids [0,1024) -> z in {0,1}
    proj3_kernel<<<3072, 256, 0, stream>>>(dlo, WTq, bq, dhi,
                                           bufA, WTv, bv, bufB,
                                           WTk, bk, dlo,
                                           kv_mask, sp_mask, bits,
                                           2, 1, 1024, 0);
    // pure gemm: 512 blocks, z = 2 (kp -> dlo)
    proj3_kernel<<<512, 256, 0, stream>>>(dlo, WTq, bq, dhi,
                                          bufA, WTv, bv, bufB,
                                          WTk, bk, dlo,
                                          kv_mask, sp_mask, bits,
                                          0, 1, 512, 2);
  }

  attn_kernel<<<1024, 256, 0, stream>>>(dhi, kp, bufB, bits, bufA);

  out_kernel<<<512, 256, 0, stream>>>(bufA, WTo, bo, (float*)d_out);
}

// Round 10
// 242.534 us; speedup vs baseline: 1.0695x; 1.0695x over previous
//
#include <hip/hip_runtime.h>
#include <hip/hip_bf16.h>
#include <math.h>

typedef unsigned short ushort_t;
typedef __attribute__((ext_vector_type(8))) __bf16 bf16x8;
typedef __attribute__((ext_vector_type(4))) float f32x4;
typedef __attribute__((ext_vector_type(16))) float f32x16;
typedef __attribute__((ext_vector_type(4))) unsigned int u32x4;

#define E_DIM 512
#define HEADS 8
#define HD 64
#define SEQ 2048
#define NROWS 8192        // B * SEQ
#define QSCALE 0.18033688011112042f   // 0.125 * log2(e): scores in log2 domain

static __device__ __forceinline__ unsigned short f2b(float f) {
  unsigned int x;
  __builtin_memcpy(&x, &f, 4);
  x += 0x7fffu + ((x >> 16) & 1u);   // RNE (cold epilogues only)
  return (unsigned short)(x >> 16);
}

// v_cvt_pk_bf16_f32: pack 2 f32 -> 2 bf16 (RNE) in one u32. No builtin on gfx950.
static __device__ __forceinline__ unsigned cvt_pk_bf16(float lo, float hi) {
  unsigned r;
  asm("v_cvt_pk_bf16_f32 %0, %1, %2" : "=v"(r) : "v"(lo), "v"(hi));
  return r;
}

// raw v_exp_f32 (2^x): skips ocml's subnormal-fixup sequence.
static __device__ __forceinline__ float fexp2(float x) {
  float r;
  asm("v_exp_f32 %0, %1" : "=v"(r) : "v"(x));
  return r;
}

// sign-extended 1-bit field extract: 0 or 0xFFFFFFFF (v_bfe_i32, 1 inst)
static __device__ __forceinline__ unsigned bitmask1(unsigned v, int off) {
#if __has_builtin(__builtin_amdgcn_sbfe)
  return (unsigned)__builtin_amdgcn_sbfe((int)v, off, 1);
#else
  return (unsigned)((int)(v << (31 - off)) >> 31);
#endif
}

// XOR-swizzled LDS index for 64-col bf16 tiles (16B chunks) — conflict-free reads.
static __device__ __forceinline__ int swz(int row, int col) {
  return row * 64 + ((((col >> 3) ^ (row & 7)) & 7) << 3) + (col & 7);
}

// Async 16B/lane global->LDS DMA; dest = lds_base + lane*16B (wave-uniform base).
// Caller realizes the swizzle by permuting the per-lane GLOBAL address.
// NOTE (R5 lesson): this staging is the COALESCING engine — MFMA fragments make lane l
// read row (l&31) (1-4KB strides, 64 lines/wave if direct-global); DMA reads contiguous
// 1KB then the scattered access hits conflict-free LDS. Direct-global K/V loads = 2.4x slower.
static __device__ __forceinline__ void gl2lds16(const ushort_t* g, ushort_t* s) {
#if __has_builtin(__builtin_amdgcn_global_load_lds)
  __builtin_amdgcn_global_load_lds(
      (const __attribute__((address_space(1))) unsigned int*)(uintptr_t)g,
      (__attribute__((address_space(3))) unsigned int*)(uintptr_t)s,
      16, 0, 0);
#else
  int l = threadIdx.x & 63;
  *(u32x4*)(s + l * 8) = *(const u32x4*)g;
#endif
}

// ---------------- prep: fused transposeW(x4) + pack_mask + 2x LayerNorm (R8 config) --------
// Mask bit order (producer+consumer agree): within each 64-k word, bit p holds
// k_local = 4*(p&15) + (p>>4). Producer: lane l's int4 covers k=4l..4l+3; ballot b_j bit l
// = mask(4l+j); word m = concat_j bits[16m..16m+16) of b_j  (4 ballots + 4 SALU slices).
__launch_bounds__(256)
__global__ void prep_kernel(const float* __restrict__ Wq, const float* __restrict__ Wk,
                            const float* __restrict__ Wv, const float* __restrict__ Wo,
                            ushort_t* __restrict__ WT,
                            const int* __restrict__ kvm, const int* __restrict__ sp,
                            unsigned long long* __restrict__ bits,
                            const float* __restrict__ xq, const float* __restrict__ xkv,
                            const float* __restrict__ gq, const float* __restrict__ bq,
                            const float* __restrict__ gkv, const float* __restrict__ bkv,
                            ushort_t* __restrict__ yq, ushort_t* __restrict__ ykv) {
  int blk = blockIdx.x;
  int t = threadIdx.x;
  if (blk < 1024) {                       // ---- weight transpose+cast
    int z = blk >> 8, rem = blk & 255;
    const float* in = (z == 0) ? Wq : (z == 1) ? Wk : (z == 2) ? Wv : Wo;
    ushort_t* o = WT + (size_t)z * E_DIM * E_DIM;
    __shared__ float tile[32 * 33];
    int tx = t & 31, ty = t >> 5;
    int n0 = (rem & 15) * 32, k0 = (rem >> 4) * 32;
#pragma unroll
    for (int i = 0; i < 4; ++i) {
      int k = ty + i * 8;
      tile[k * 33 + tx] = in[(k0 + k) * E_DIM + n0 + tx];
    }
    __syncthreads();
#pragma unroll
    for (int i = 0; i < 4; ++i) {
      int n = ty + i * 8;
      o[(n0 + n) * E_DIM + k0 + tx] = f2b(tile[tx * 33 + n]);
    }
  } else if (blk < 3072) {                // ---- mask pack (int4-vectorized, ballot)
    int w = t >> 6, l = t & 63;
    int row = (blk - 1024) * 4 + w;
    int b = row >> 11;
    const int4* sprow = (const int4*)(sp + ((size_t)row << 11));
    const int4* kvrow = (const int4*)(kvm + ((size_t)b << 11));
    unsigned long long* out = bits + ((size_t)row << 5);
#pragma unroll
    for (int it = 0; it < 8; ++it) {
      int4 s4 = sprow[it * 64 + l];
      int4 k4 = kvrow[it * 64 + l];
      unsigned nib = (unsigned)((s4.x && k4.x) ? 1 : 0) | ((s4.y && k4.y) ? 2u : 0)
                   | ((s4.z && k4.z) ? 4u : 0) | ((s4.w && k4.w) ? 8u : 0);
      unsigned long long b0 = __ballot((nib & 1u) != 0);
      unsigned long long b1 = __ballot((nib & 2u) != 0);
      unsigned long long b2 = __ballot((nib & 4u) != 0);
      unsigned long long b3 = __ballot((nib & 8u) != 0);
      if (l < 4) {
        int m16 = l * 16;
        unsigned long long wv = ((b0 >> m16) & 0xFFFFull)
                              | (((b1 >> m16) & 0xFFFFull) << 16)
                              | (((b2 >> m16) & 0xFFFFull) << 32)
                              | (((b3 >> m16) & 0xFFFFull) << 48);
        out[it * 4 + l] = wv;
      }
    }
  } else {                                // ---- LayerNorm, both tensors
    int idx = blk - 3072;
    int which = idx >> 11;
    const float* x = which ? xkv : xq;
    const float* g = which ? gkv : gq;
    const float* bb = which ? bkv : bq;
    ushort_t* y = which ? ykv : yq;
    int w = t >> 6, l = t & 63;
    int row = (idx & 2047) * 4 + w;
    f32x4 x0 = *(const f32x4*)&x[row * E_DIM + l * 8];
    f32x4 x1 = *(const f32x4*)&x[row * E_DIM + l * 8 + 4];
    float xf[8], s = 0.f, ss = 0.f;
#pragma unroll
    for (int j = 0; j < 8; ++j) {
      xf[j] = (j < 4) ? x0[j] : x1[j - 4];
      s += xf[j];
      ss += xf[j] * xf[j];
    }
#pragma unroll
    for (int off = 32; off > 0; off >>= 1) {
      s += __shfl_xor(s, off);
      ss += __shfl_xor(ss, off);
    }
    float mu = s * (1.f / 512.f);
    float var = fmaxf(ss * (1.f / 512.f) - mu * mu, 0.f);
    float rs = rsqrtf(var + 1e-5f);
    f32x4 g0 = *(const f32x4*)&g[l * 8];
    f32x4 g1 = *(const f32x4*)&g[l * 8 + 4];
    f32x4 b0 = *(const f32x4*)&bb[l * 8];
    f32x4 b1 = *(const f32x4*)&bb[l * 8 + 4];
#pragma unroll
    for (int j = 0; j < 8; ++j) {
      float gv = (j < 4) ? g0[j] : g1[j - 4];
      float bv = (j < 4) ? b0[j] : b1[j - 4];
      y[row * E_DIM + l * 8 + j] = f2b((xf[j] - mu) * rs * gv + bv);
    }
  }
}

// ------- GEMM core, 128x64 tile, 2 K-chunks per barrier-pair (R10: attn's ILP lever) -------
// 8 K-iters x 2 barriers was phase-starved: ~80 cyc MFMA between barriers vs ~900 cyc DMA
// latency. Staging TWO BK=64 chunks per phase halves barrier-pairs (4) and doubles per-phase
// compute (32 MFMA). LDS 48KB (lA 2x16K + lB 2x8K) -> 3 blocks/CU.
// MODE 0: bf16 row-major C (with scale)  MODE 1: fp32 row-major C
// MODE 2: bf16 Vt-transposed epilogue  Vt[((b*8+h)*64+d)*2048 + k]  (packed uint2 along k)
template <int MODE>
static __device__ __forceinline__ void gemm_core64(ushort_t* lA, ushort_t* lB,
                                                   const ushort_t* __restrict__ A,
                                                   const ushort_t* __restrict__ WT,
                                                   const float* __restrict__ bias,
                                                   void* Cv, float scale, int m0, int n0) {
  int t = threadIdx.x, w = t >> 6, l = t & 63;
  int quad = l >> 4, l15 = l & 15;
  int wm_ = w >> 1, wn_ = w & 1;
  int csrc = ((l & 7) ^ (l >> 3)) * 8;   // swizzle folded into per-lane global column
  int rln = l >> 3;

  f32x4 acc[4][2] = {};
  for (int kk = 0; kk < E_DIM; kk += 128) {
    __syncthreads();
#pragma unroll
    for (int h2 = 0; h2 < 2; ++h2) {     // stage two BK=64 chunks
      ushort_t* A_ = lA + h2 * (128 * 64);
      ushort_t* B_ = lB + h2 * (64 * 64);
      int kks = kk + h2 * 64;
#pragma unroll
      for (int i = 0; i < 4; ++i) {      // A: 128 rows
        int r0 = i * 32 + w * 8;
        gl2lds16(&A[(size_t)(m0 + r0 + rln) * E_DIM + kks + csrc], &A_[r0 * 64]);
      }
#pragma unroll
      for (int i = 0; i < 2; ++i) {      // B: 64 rows
        int r0 = i * 32 + w * 8;
        gl2lds16(&WT[(size_t)(n0 + r0 + rln) * E_DIM + kks + csrc], &B_[r0 * 64]);
      }
    }
    __syncthreads();
#pragma unroll
    for (int h2 = 0; h2 < 2; ++h2) {     // compute both chunks (32 MFMA between barriers)
      ushort_t* A_ = lA + h2 * (128 * 64);
      ushort_t* B_ = lB + h2 * (64 * 64);
#pragma unroll
      for (int ks = 0; ks < 2; ++ks) {
        bf16x8 af[4], bf[2];
#pragma unroll
        for (int mt = 0; mt < 4; ++mt)
          af[mt] = *(const bf16x8*)&A_[swz(wm_ * 64 + mt * 16 + l15, ks * 32 + quad * 8)];
#pragma unroll
        for (int nt = 0; nt < 2; ++nt)
          bf[nt] = *(const bf16x8*)&B_[swz(wn_ * 32 + nt * 16 + l15, ks * 32 + quad * 8)];
#pragma unroll
        for (int mt = 0; mt < 4; ++mt)
#pragma unroll
          for (int nt = 0; nt < 2; ++nt)
            acc[mt][nt] = __builtin_amdgcn_mfma_f32_16x16x32_bf16(af[mt], bf[nt], acc[mt][nt], 0, 0, 0);
      }
    }
  }

#pragma unroll
  for (int nt = 0; nt < 2; ++nt) {
    int col = n0 + wn_ * 32 + nt * 16 + l15;
    float bv = bias[col];
    if constexpr (MODE == 2) {
      int h = col >> 6, d = col & 63;
#pragma unroll
      for (int mt = 0; mt < 4; ++mt) {
        int row = m0 + wm_ * 64 + mt * 16 + quad * 4;   // 4 consecutive k (r=0..3)
        int b = row >> 11, k = row & 2047;
        union { ushort_t u[4]; uint2 v; } pk;
#pragma unroll
        for (int r = 0; r < 4; ++r) pk.u[r] = f2b(acc[mt][nt][r] + bv);
        *(uint2*)&((ushort_t*)Cv)[((((size_t)(b * HEADS + h)) * HD + d) << 11) + k] = pk.v;
      }
    } else {
#pragma unroll
      for (int mt = 0; mt < 4; ++mt) {
#pragma unroll
        for (int r = 0; r < 4; ++r) {
          int rowm = m0 + wm_ * 64 + mt * 16 + quad * 4 + r;   // C/D: col=l&15, row=quad*4+r
          float val = (acc[mt][nt][r] + bv) * scale;
          if constexpr (MODE == 0)
            ((ushort_t*)Cv)[rowm * E_DIM + col] = f2b(val);
          else
            ((float*)Cv)[rowm * E_DIM + col] = val;
        }
      }
    }
  }
}

// Fused projections (R3/R8 schedule). Grid = 512*nz blocks, XCD-bijective chunking.
// z = zbase + work/512:  0: qp=(qn@WTq+bq)*QSCALE   1: Vt=T(kvn@WTv+bv)   2: kp=kvn@WTk+bk
__launch_bounds__(256)
__global__ void proj3_kernel(const ushort_t* __restrict__ qn, const ushort_t* __restrict__ WTq,
                             const float* __restrict__ bq, ushort_t* __restrict__ qp,
                             const ushort_t* __restrict__ kvn, const ushort_t* __restrict__ WTv,
                             const float* __restrict__ bv, ushort_t* __restrict__ Vt,
                             const ushort_t* __restrict__ WTk, const float* __restrict__ bk,
                             ushort_t* __restrict__ kp, int zbase) {
  __shared__ ushort_t lA[2 * 128 * 64];
  __shared__ ushort_t lB[2 * 64 * 64];
  int flat = blockIdx.x;
  int chunk = gridDim.x >> 3;
  int work = (flat & 7) * chunk + (flat >> 3);
  int z = zbase + (work >> 9);
  int r = work & 511;
  int m0 = (r >> 3) * 128, n0 = (r & 7) * 64;
  if (z == 0)      gemm_core64<0>(lA, lB, qn,  WTq, bq, qp, QSCALE, m0, n0);
  else if (z == 1) gemm_core64<2>(lA, lB, kvn, WTv, bv, Vt, 1.f,    m0, n0);
  else             gemm_core64<0>(lA, lB, kvn, WTk, bk, kp, 1.f,    m0, n0);
}

// Output GEMM: ctx@WTo+bo -> fp32. 512 blocks, XCD-chunked.
__launch_bounds__(256)
__global__ void out_kernel(const ushort_t* __restrict__ A, const ushort_t* __restrict__ WT,
                           const float* __restrict__ bias, float* __restrict__ C) {
  __shared__ ushort_t lA[2 * 128 * 64];
  __shared__ ushort_t lB[2 * 64 * 64];
  int flat = blockIdx.x;
  int work = (flat & 7) * 64 + (flat >> 3);
  int m0 = (work >> 3) * 128, n0 = (work & 7) * 64;
  gemm_core64<1>(lA, lB, A, WT, bias, C, 1.f, m0, n0);
}

// softmax + in-register P->B-fragment build for one 64-k tile (two 32x32 halves).
// Mask bit order: element (kt2,half,g,r) -> bit (8*kt2+2*g+half)+16*(r&1) of (r<2?lo:hi).
static __device__ __forceinline__ void softmax_frag(const f32x16& s0, const f32x16& s1,
                                                    unsigned mlo, unsigned mhi, int half,
                                                    bf16x8* pf, f32x16* dummy_unused) {
#pragma unroll
  for (int kt2 = 0; kt2 < 2; ++kt2) {
    const f32x16& sv = kt2 ? s1 : s0;
    unsigned wa[4], wb[4];
#pragma unroll
    for (int g = 0; g < 4; ++g) {
      int bb = 8 * kt2 + 2 * g + half;
      unsigned q0u = __float_as_uint(fexp2(sv[g * 4 + 0])) & bitmask1(mlo, bb);
      unsigned q1u = __float_as_uint(fexp2(sv[g * 4 + 1])) & bitmask1(mlo, bb + 16);
      unsigned q2u = __float_as_uint(fexp2(sv[g * 4 + 2])) & bitmask1(mhi, bb);
      unsigned q3u = __float_as_uint(fexp2(sv[g * 4 + 3])) & bitmask1(mhi, bb + 16);
      wa[g] = cvt_pk_bf16(__uint_as_float(q0u), __uint_as_float(q1u));
      wb[g] = cvt_pk_bf16(__uint_as_float(q2u), __uint_as_float(q3u));
    }
    asm("v_permlane32_swap_b32 %0, %1" : "+v"(wa[0]), "+v"(wa[1]));
    asm("v_permlane32_swap_b32 %0, %1" : "+v"(wb[0]), "+v"(wb[1]));
    asm("v_permlane32_swap_b32 %0, %1" : "+v"(wa[2]), "+v"(wa[3]));
    asm("v_permlane32_swap_b32 %0, %1" : "+v"(wb[2]), "+v"(wb[3]));
    union { unsigned u[4]; bf16x8 v; } f0, f1;
    f0.u[0] = wa[0]; f0.u[1] = wb[0]; f0.u[2] = wa[1]; f0.u[3] = wb[1];
    f1.u[0] = wa[2]; f1.u[1] = wb[2]; f1.u[2] = wa[3]; f1.u[3] = wb[3];
    pf[kt2 * 2 + 0] = f0.v;
    pf[kt2 * 2 + 1] = f1.v;
  }
}

// ---------------- flash attention: 2-tile ILP build (R8 — best measured, CONTROL) ----------
// ILP-NOT-OCCUPANCY: R1/R6/R7 proved occupancy is register-capped (~2-3 waves/SIMD, unified
// VGPR+AGPR); latency-hiding comes from TWO independent k-tiles (A,B) per iteration —
// QK/SM/PV chains interleave, barriers per tile halve. 256 threads = (2 q-waves) x
// (2 k-slices); slice ks handles kt = 4*t8 + 2*ks + {0,1}. Partials additive (no-max log2
// softmax) -> 2-way LDS merge. LDS 72KB. XCD-bijective swizzle keeps (b,h) K/V on one XCD L2.
// LDS staging kept: it is the coalescing engine (R5: direct-global = 2.4x slower).
__launch_bounds__(256)
__global__ void attn_kernel(const ushort_t* __restrict__ Qp, const ushort_t* __restrict__ Kp,
                            const ushort_t* __restrict__ Vt,
                            const unsigned long long* __restrict__ bits,
                            ushort_t* __restrict__ ctx) {
  __shared__ __align__(16) char smemb[73728];
  ushort_t* sQ = (ushort_t*)smemb;                        // [0, 8192) — never reused in loop
  int t = threadIdx.x, w = t >> 6, l = t & 63;
  int qw = w & 1, ks = w >> 1;                            // ks in {0,1}
  ushort_t* sKA = (ushort_t*)(smemb + 8192 + ks * 16384); // [8192, 40960)
  ushort_t* sKB = sKA + 4096;
  ushort_t* sVA = (ushort_t*)(smemb + 40960 + ks * 16384);// [40960, 73728)
  ushort_t* sVB = sVA + 4096;
  int l31 = l & 31, half = l >> 5;

  int flat = blockIdx.x;
  int work = (flat & 7) * 128 + (flat >> 3);   // bijective XCD chunking (1024 = 8*128)
  int qblk = work & 31;
  int h = (work >> 5) & 7;
  int b = work >> 8;
  int q0 = qblk * 64;
  int bh = b * HEADS + h;
  int myq = qw * 32 + l31;
  int csrc = ((l & 7) ^ (l >> 3)) * 8;
  int rln = l >> 3;

  // prologue: stage Q (64 rows, 8 DMAs across 4 waves), drain, read loop-invariant frags
#pragma unroll
  for (int it = 0; it < 2; ++it) {
    int r0 = w * 16 + it * 8;
    gl2lds16(&Qp[(size_t)(b * SEQ + q0 + r0 + rln) * E_DIM + h * HD + csrc], &sQ[r0 * 64]);
  }
  __syncthreads();
  bf16x8 qf[4];
#pragma unroll
  for (int ds = 0; ds < 4; ++ds)
    qf[ds] = *(const bf16x8*)&sQ[swz(myq, ds * 16 + 8 * half)];

  const unsigned long long* mrow = bits + ((size_t)(b * SEQ + q0 + myq) << 5);
  f32x16 o0 = {}, o1 = {}, lacc = {};
  union { unsigned u[4]; bf16x8 v; } onec;
#pragma unroll
  for (int i = 0; i < 4; ++i) onec.u[i] = 0x3f803f80u;   // bf16 1.0 pairs

  for (int t8 = 0; t8 < 8; ++t8) {
    int ktA = t8 * 4 + ks * 2;
    int kA0 = ktA * 64, kB0 = kA0 + 64;
    unsigned long long mA = mrow[ktA], mB = mrow[ktA + 1];
    __syncthreads();   // prev iteration's sK/sV reads done (both slices)
    // stage tiles A and B for this slice (2 waves x 16 DMAs)
#pragma unroll
    for (int it = 0; it < 4; ++it) {
      int r0 = (it * 2 + qw) * 8;
      gl2lds16(&Kp[(size_t)(b * SEQ + kA0 + r0 + rln) * E_DIM + h * HD + csrc], &sKA[r0 * 64]);
      gl2lds16(&Kp[(size_t)(b * SEQ + kB0 + r0 + rln) * E_DIM + h * HD + csrc], &sKB[r0 * 64]);
      gl2lds16(&Vt[((size_t)bh * HD + r0 + rln) * SEQ + kA0 + csrc], &sVA[r0 * 64]);
      gl2lds16(&Vt[((size_t)bh * HD + r0 + rln) * SEQ + kB0 + csrc], &sVB[r0 * 64]);
    }
    __syncthreads();   // DMA drained

    // QK^T for both tiles — independent chains, compiler interleaves
    f32x16 sA0 = {}, sA1 = {}, sB0 = {}, sB1 = {};
    __builtin_amdgcn_s_setprio(1);
#pragma unroll
    for (int ds = 0; ds < 4; ++ds) {
      bf16x8 kfA0 = *(const bf16x8*)&sKA[swz(l31, ds * 16 + 8 * half)];
      bf16x8 kfA1 = *(const bf16x8*)&sKA[swz(32 + l31, ds * 16 + 8 * half)];
      bf16x8 kfB0 = *(const bf16x8*)&sKB[swz(l31, ds * 16 + 8 * half)];
      bf16x8 kfB1 = *(const bf16x8*)&sKB[swz(32 + l31, ds * 16 + 8 * half)];
      sA0 = __builtin_amdgcn_mfma_f32_32x32x16_bf16(kfA0, qf[ds], sA0, 0, 0, 0);
      sA1 = __builtin_amdgcn_mfma_f32_32x32x16_bf16(kfA1, qf[ds], sA1, 0, 0, 0);
      sB0 = __builtin_amdgcn_mfma_f32_32x32x16_bf16(kfB0, qf[ds], sB0, 0, 0, 0);
      sB1 = __builtin_amdgcn_mfma_f32_32x32x16_bf16(kfB1, qf[ds], sB1, 0, 0, 0);
    }
    __builtin_amdgcn_s_setprio(0);

    // softmax for both tiles (independent VALU chains)
    bf16x8 pfA[4], pfB[4];
    softmax_frag(sA0, sA1, (unsigned)mA, (unsigned)(mA >> 32), half, pfA, nullptr);
    softmax_frag(sB0, sB1, (unsigned)mB, (unsigned)(mB >> 32), half, pfB, nullptr);

    // O^T += V^T P^T for both tiles ; lacc += 1^T P^T (row-sums on the MFMA pipe)
    __builtin_amdgcn_s_setprio(1);
#pragma unroll
    for (int ksp = 0; ksp < 4; ++ksp) {
      bf16x8 vfA0 = *(const bf16x8*)&sVA[swz(l31, ksp * 16 + 8 * half)];
      bf16x8 vfA1 = *(const bf16x8*)&sVA[swz(32 + l31, ksp * 16 + 8 * half)];
      o0 = __builtin_amdgcn_mfma_f32_32x32x16_bf16(vfA0, pfA[ksp], o0, 0, 0, 0);
      o1 = __builtin_amdgcn_mfma_f32_32x32x16_bf16(vfA1, pfA[ksp], o1, 0, 0, 0);
      lacc = __builtin_amdgcn_mfma_f32_32x32x16_bf16(onec.v, pfA[ksp], lacc, 0, 0, 0);
      bf16x8 vfB0 = *(const bf16x8*)&sVB[swz(l31, ksp * 16 + 8 * half)];
      bf16x8 vfB1 = *(const bf16x8*)&sVB[swz(32 + l31, ksp * 16 + 8 * half)];
      o0 = __builtin_amdgcn_mfma_f32_32x32x16_bf16(vfB0, pfB[ksp], o0, 0, 0, 0);
      o1 = __builtin_amdgcn_mfma_f32_32x32x16_bf16(vfB1, pfB[ksp], o1, 0, 0, 0);
      lacc = __builtin_amdgcn_mfma_f32_32x32x16_bf16(onec.v, pfB[ksp], lacc, 0, 0, 0);
    }
    __builtin_amdgcn_s_setprio(0);
  }

  // lacc[0] = full slice row-sum for q=lane&31 (identical in both halves)
  float lsum = lacc[0];

  // cross-slice merge: slice 1 writes partials to LDS (K area dead), slice 0 adds.
  __syncthreads();                       // all compute done before overwriting K area
  float* mrg = (float*)(smemb + 8192);   // [2 qw][64 lanes][33 floats] = 16.9KB
  if (ks == 1) {
    float* e = mrg + (qw * 64 + l) * 33;
#pragma unroll
    for (int r = 0; r < 16; ++r) e[r] = o0[r];
#pragma unroll
    for (int r = 0; r < 16; ++r) e[16 + r] = o1[r];
    e[32] = lsum;
  }
  __syncthreads();
  if (ks == 0) {
    const float* e = mrg + (qw * 64 + l) * 33;
#pragma unroll
    for (int r = 0; r < 16; ++r) o0[r] += e[r];
#pragma unroll
    for (int r = 0; r < 16; ++r) o1[r] += e[16 + r];
    lsum += e[32];
    float inv = (lsum > 0.f) ? 1.f / lsum : 0.f;   // all-masked row -> 0 (nan_to_num)
    size_t base = (size_t)(b * SEQ + q0 + myq) * E_DIM + h * HD;
#pragma unroll
    for (int dt = 0; dt < 2; ++dt) {
      const f32x16& oo = dt ? o1 : o0;
#pragma unroll
      for (int g = 0; g < 4; ++g) {
        union { ushort_t u[4]; uint2 v; } ov;
#pragma unroll
        for (int r = 0; r < 4; ++r) ov.u[r] = f2b(oo[g * 4 + r] * inv);
        *(uint2*)&ctx[base + dt * 32 + g * 8 + 4 * half] = ov.v;   // d=(r)+8g+4*half+32dt
      }
    }
  }
}

// ---------------- launch (R8 schedule) ----------------
// fp32 in/out, bf16 internals. d_out (16 MB fp32) = two 8 MB bf16 slots dlo/dhi.
// Preferred (ws >= 28 MiB): bufA(8) bufB(8) WT(2) bits(2) bufC(8):
//   1 prep:  WT, bits, qn->dlo, kvn->bufA                 (7168 blocks)
//   2 proj3: qp->dhi, Vt->bufB, kp->bufC                  (1536 blocks)
//   3 attn:  (dhi, bufC, bufB, bits) -> bufA              (1024 x 256)
//   4 out:   bufA@WTo+bo -> d_out fp32                    (512)
// Fallback (ws < 28 MiB): proj3 split into (q,v) then (k->dlo).
extern "C" void kernel_launch(void* const* d_in, const int* in_sizes, int n_in,
                              void* d_out, int out_size, void* d_ws, size_t ws_size,
                              hipStream_t stream) {
  const float* query     = (const float*)d_in[0];
  const float* key_value = (const float*)d_in[1];
  const int*   kv_mask   = (const int*)d_in[2];
  const int*   sp_mask   = (const int*)d_in[3];
  const float* ln_q_g  = (const float*)d_in[4];
  const float* ln_q_b  = (const float*)d_in[5];
  const float* ln_kv_g = (const float*)d_in[6];
  const float* ln_kv_b = (const float*)d_in[7];
  const float* Wq = (const float*)d_in[8];
  const float* bq = (const float*)d_in[9];
  const float* Wk = (const float*)d_in[10];
  const float* bk = (const float*)d_in[11];
  const float* Wv = (const float*)d_in[12];
  const float* bv = (const float*)d_in[13];
  const float* Wo = (const float*)d_in[14];
  const float* bo = (const float*)d_in[15];

  const size_t NB = (size_t)NROWS * E_DIM;       // 8 MiB bf16 slot
  char* ws = (char*)d_ws;
  ushort_t* bufA = (ushort_t*)ws;                // kvn -> ctx
  ushort_t* bufB = bufA + NB;                    // Vt
  ushort_t* WT   = bufB + NB;                    // 4 x 512x512 bf16 = 2 MiB
  ushort_t* WTq = WT;
  ushort_t* WTk = WTq + E_DIM * E_DIM;
  ushort_t* WTv = WTk + E_DIM * E_DIM;
  ushort_t* WTo = WTv + E_DIM * E_DIM;
  unsigned long long* bits = (unsigned long long*)(WTo + E_DIM * E_DIM);  // 2 MiB
  ushort_t* bufC = (ushort_t*)(ws + (20u << 20));                         // kp (8 MiB)

  ushort_t* dlo = (ushort_t*)d_out;              // qn, then (fallback) kp
  ushort_t* dhi = dlo + NB;                      // qp

  bool fused = ws_size >= (28u << 20);
  ushort_t* kp = fused ? bufC : dlo;

  prep_kernel<<<7168, 256, 0, stream>>>(Wq, Wk, Wv, Wo, WT, kv_mask, sp_mask, bits,
                                        query, key_value, ln_q_g, ln_q_b, ln_kv_g, ln_kv_b,
                                        dlo, bufA);

  if (fused) {
    proj3_kernel<<<1536, 256, 0, stream>>>(dlo, WTq, bq, dhi,
                                           bufA, WTv, bv, bufB,
                                           WTk, bk, bufC, 0);
  } else {
    proj3_kernel<<<1024, 256, 0, stream>>>(dlo, WTq, bq, dhi,
                                           bufA, WTv, bv, bufB,
                                           WTk, bk, dlo, 0);       // z in {0,1}: kp unused
    proj3_kernel<<<512, 256, 0, stream>>>(dlo, WTq, bq, dhi,
                                          bufA, WTv, bv, bufB,
                                          WTk, bk, dlo, 2);        // z = 2: kp -> dlo
  }

  attn_kernel<<<1024, 256, 0, stream>>>(dhi, kp, bufB, bits, bufA);

  out_kernel<<<512, 256, 0, stream>>>(bufA, WTo, bo, (float*)d_out);
}

// Round 11
// 239.536 us; speedup vs baseline: 1.0828x; 1.0125x over previous
//
#include <hip/hip_runtime.h>
#include <hip/hip_bf16.h>
#include <math.h>

typedef unsigned short ushort_t;
typedef __attribute__((ext_vector_type(8))) __bf16 bf16x8;
typedef __attribute__((ext_vector_type(4))) float f32x4;
typedef __attribute__((ext_vector_type(16))) float f32x16;
typedef __attribute__((ext_vector_type(4))) unsigned int u32x4;

#define E_DIM 512
#define HEADS 8
#define HD 64
#define SEQ 2048
#define NROWS 8192        // B * SEQ
#define QSCALE 0.18033688011112042f   // 0.125 * log2(e): scores in log2 domain

static __device__ __forceinline__ unsigned short f2b(float f) {
  unsigned int x;
  __builtin_memcpy(&x, &f, 4);
  x += 0x7fffu + ((x >> 16) & 1u);   // RNE (cold epilogues only)
  return (unsigned short)(x >> 16);
}

// v_cvt_pk_bf16_f32: pack 2 f32 -> 2 bf16 (RNE) in one u32. No builtin on gfx950.
static __device__ __forceinline__ unsigned cvt_pk_bf16(float lo, float hi) {
  unsigned r;
  asm("v_cvt_pk_bf16_f32 %0, %1, %2" : "=v"(r) : "v"(lo), "v"(hi));
  return r;
}

// raw v_exp_f32 (2^x): skips ocml's subnormal-fixup sequence.
static __device__ __forceinline__ float fexp2(float x) {
  float r;
  asm("v_exp_f32 %0, %1" : "=v"(r) : "v"(x));
  return r;
}

// sign-extended 1-bit field extract: 0 or 0xFFFFFFFF (v_bfe_i32, 1 inst)
static __device__ __forceinline__ unsigned bitmask1(unsigned v, int off) {
#if __has_builtin(__builtin_amdgcn_sbfe)
  return (unsigned)__builtin_amdgcn_sbfe((int)v, off, 1);
#else
  return (unsigned)((int)(v << (31 - off)) >> 31);
#endif
}

// XOR-swizzled LDS index for 64-col bf16 tiles (16B chunks) — conflict-free reads.
static __device__ __forceinline__ int swz(int row, int col) {
  return row * 64 + ((((col >> 3) ^ (row & 7)) & 7) << 3) + (col & 7);
}

// Async 16B/lane global->LDS DMA; dest = lds_base + lane*16B (wave-uniform base).
// Caller realizes the swizzle by permuting the per-lane GLOBAL address.
// NOTE (R5 lesson): this staging is the COALESCING engine — MFMA fragments make lane l
// read row (l&31) (1-4KB strides, 64 lines/wave if direct-global); DMA reads contiguous
// 1KB then the scattered access hits conflict-free LDS. Direct-global K/V loads = 2.4x slower.
static __device__ __forceinline__ void gl2lds16(const ushort_t* g, ushort_t* s) {
#if __has_builtin(__builtin_amdgcn_global_load_lds)
  __builtin_amdgcn_global_load_lds(
      (const __attribute__((address_space(1))) unsigned int*)(uintptr_t)g,
      (__attribute__((address_space(3))) unsigned int*)(uintptr_t)s,
      16, 0, 0);
#else
  int l = threadIdx.x & 63;
  *(u32x4*)(s + l * 8) = *(const u32x4*)g;
#endif
}

// ---------------- prep: fused transposeW(x4) + pack_mask + 2x LayerNorm (R8 config) --------
// Mask bit order (producer+consumer agree): within each 64-k word, bit p holds
// k_local = 4*(p&15) + (p>>4). Producer: lane l's int4 covers k=4l..4l+3; ballot b_j bit l
// = mask(4l+j); word m = concat_j bits[16m..16m+16) of b_j  (4 ballots + 4 SALU slices).
__launch_bounds__(256)
__global__ void prep_kernel(const float* __restrict__ Wq, const float* __restrict__ Wk,
                            const float* __restrict__ Wv, const float* __restrict__ Wo,
                            ushort_t* __restrict__ WT,
                            const int* __restrict__ kvm, const int* __restrict__ sp,
                            unsigned long long* __restrict__ bits,
                            const float* __restrict__ xq, const float* __restrict__ xkv,
                            const float* __restrict__ gq, const float* __restrict__ bq,
                            const float* __restrict__ gkv, const float* __restrict__ bkv,
                            ushort_t* __restrict__ yq, ushort_t* __restrict__ ykv) {
  int blk = blockIdx.x;
  int t = threadIdx.x;
  if (blk < 1024) {                       // ---- weight transpose+cast
    int z = blk >> 8, rem = blk & 255;
    const float* in = (z == 0) ? Wq : (z == 1) ? Wk : (z == 2) ? Wv : Wo;
    ushort_t* o = WT + (size_t)z * E_DIM * E_DIM;
    __shared__ float tile[32 * 33];
    int tx = t & 31, ty = t >> 5;
    int n0 = (rem & 15) * 32, k0 = (rem >> 4) * 32;
#pragma unroll
    for (int i = 0; i < 4; ++i) {
      int k = ty + i * 8;
      tile[k * 33 + tx] = in[(k0 + k) * E_DIM + n0 + tx];
    }
    __syncthreads();
#pragma unroll
    for (int i = 0; i < 4; ++i) {
      int n = ty + i * 8;
      o[(n0 + n) * E_DIM + k0 + tx] = f2b(tile[tx * 33 + n]);
    }
  } else if (blk < 3072) {                // ---- mask pack (int4-vectorized, ballot)
    int w = t >> 6, l = t & 63;
    int row = (blk - 1024) * 4 + w;
    int b = row >> 11;
    const int4* sprow = (const int4*)(sp + ((size_t)row << 11));
    const int4* kvrow = (const int4*)(kvm + ((size_t)b << 11));
    unsigned long long* out = bits + ((size_t)row << 5);
#pragma unroll
    for (int it = 0; it < 8; ++it) {
      int4 s4 = sprow[it * 64 + l];
      int4 k4 = kvrow[it * 64 + l];
      unsigned nib = (unsigned)((s4.x && k4.x) ? 1 : 0) | ((s4.y && k4.y) ? 2u : 0)
                   | ((s4.z && k4.z) ? 4u : 0) | ((s4.w && k4.w) ? 8u : 0);
      unsigned long long b0 = __ballot((nib & 1u) != 0);
      unsigned long long b1 = __ballot((nib & 2u) != 0);
      unsigned long long b2 = __ballot((nib & 4u) != 0);
      unsigned long long b3 = __ballot((nib & 8u) != 0);
      if (l < 4) {
        int m16 = l * 16;
        unsigned long long wv = ((b0 >> m16) & 0xFFFFull)
                              | (((b1 >> m16) & 0xFFFFull) << 16)
                              | (((b2 >> m16) & 0xFFFFull) << 32)
                              | (((b3 >> m16) & 0xFFFFull) << 48);
        out[it * 4 + l] = wv;
      }
    }
  } else {                                // ---- LayerNorm, both tensors
    int idx = blk - 3072;
    int which = idx >> 11;
    const float* x = which ? xkv : xq;
    const float* g = which ? gkv : gq;
    const float* bb = which ? bkv : bq;
    ushort_t* y = which ? ykv : yq;
    int w = t >> 6, l = t & 63;
    int row = (idx & 2047) * 4 + w;
    f32x4 x0 = *(const f32x4*)&x[row * E_DIM + l * 8];
    f32x4 x1 = *(const f32x4*)&x[row * E_DIM + l * 8 + 4];
    float xf[8], s = 0.f, ss = 0.f;
#pragma unroll
    for (int j = 0; j < 8; ++j) {
      xf[j] = (j < 4) ? x0[j] : x1[j - 4];
      s += xf[j];
      ss += xf[j] * xf[j];
    }
#pragma unroll
    for (int off = 32; off > 0; off >>= 1) {
      s += __shfl_xor(s, off);
      ss += __shfl_xor(ss, off);
    }
    float mu = s * (1.f / 512.f);
    float var = fmaxf(ss * (1.f / 512.f) - mu * mu, 0.f);
    float rs = rsqrtf(var + 1e-5f);
    f32x4 g0 = *(const f32x4*)&g[l * 8];
    f32x4 g1 = *(const f32x4*)&g[l * 8 + 4];
    f32x4 b0 = *(const f32x4*)&bb[l * 8];
    f32x4 b1 = *(const f32x4*)&bb[l * 8 + 4];
#pragma unroll
    for (int j = 0; j < 8; ++j) {
      float gv = (j < 4) ? g0[j] : g1[j - 4];
      float bv = (j < 4) ? b0[j] : b1[j - 4];
      y[row * E_DIM + l * 8 + j] = f2b((xf[j] - mu) * rs * gv + bv);
    }
  }
}

// ------- GEMM core, 128x64 tile, TRUE 2-phase double-buffer (R11: T3 minimum recipe) -------
// R10 still EXPOSED the DMA flight (stage; drain-barrier; compute). Correct 2-phase:
//   STAGE(b0); loop { sync; STAGE(b^1, next); compute(b) }
// The sync at iter t drains DMAs issued at t-1 (they flew under a full compute phase of
// 16 MFMA + ds_reads) AND guarantees all waves finished computing the buffer about to be
// overwritten. Zero exposed DMA latency; 8 barriers total (1/iter). LDS 48KB -> 3 blocks/CU.
// MODE 0: bf16 row-major C (with scale)  MODE 1: fp32 row-major C
// MODE 2: bf16 Vt-transposed epilogue  Vt[((b*8+h)*64+d)*2048 + k]  (packed uint2 along k)
template <int MODE>
static __device__ __forceinline__ void gemm_core64(ushort_t* lA, ushort_t* lB,
                                                   const ushort_t* __restrict__ A,
                                                   const ushort_t* __restrict__ WT,
                                                   const float* __restrict__ bias,
                                                   void* Cv, float scale, int m0, int n0) {
  int t = threadIdx.x, w = t >> 6, l = t & 63;
  int quad = l >> 4, l15 = l & 15;
  int wm_ = w >> 1, wn_ = w & 1;
  int csrc = ((l & 7) ^ (l >> 3)) * 8;   // swizzle folded into per-lane global column
  int rln = l >> 3;

  // stage one BK=64 chunk into buffer parity `buf`
  auto STAGE = [&](int buf, int kks) {
    ushort_t* A_ = lA + buf * (128 * 64);
    ushort_t* B_ = lB + buf * (64 * 64);
#pragma unroll
    for (int i = 0; i < 4; ++i) {        // A: 128 rows
      int r0 = i * 32 + w * 8;
      gl2lds16(&A[(size_t)(m0 + r0 + rln) * E_DIM + kks + csrc], &A_[r0 * 64]);
    }
#pragma unroll
    for (int i = 0; i < 2; ++i) {        // B: 64 rows
      int r0 = i * 32 + w * 8;
      gl2lds16(&WT[(size_t)(n0 + r0 + rln) * E_DIM + kks + csrc], &B_[r0 * 64]);
    }
  };

  f32x4 acc[4][2] = {};
  STAGE(0, 0);                           // prologue
  for (int tt = 0; tt < 8; ++tt) {       // 8 BK=64 chunks
    __syncthreads();                     // drains DMAs for buf tt&1; prev compute done
    if (tt < 7) STAGE((tt + 1) & 1, (tt + 1) * 64);   // next chunk flies under compute
    ushort_t* A_ = lA + (tt & 1) * (128 * 64);
    ushort_t* B_ = lB + (tt & 1) * (64 * 64);
#pragma unroll
    for (int ks = 0; ks < 2; ++ks) {
      bf16x8 af[4], bf[2];
#pragma unroll
      for (int mt = 0; mt < 4; ++mt)
        af[mt] = *(const bf16x8*)&A_[swz(wm_ * 64 + mt * 16 + l15, ks * 32 + quad * 8)];
#pragma unroll
      for (int nt = 0; nt < 2; ++nt)
        bf[nt] = *(const bf16x8*)&B_[swz(wn_ * 32 + nt * 16 + l15, ks * 32 + quad * 8)];
#pragma unroll
      for (int mt = 0; mt < 4; ++mt)
#pragma unroll
        for (int nt = 0; nt < 2; ++nt)
          acc[mt][nt] = __builtin_amdgcn_mfma_f32_16x16x32_bf16(af[mt], bf[nt], acc[mt][nt], 0, 0, 0);
    }
  }

#pragma unroll
  for (int nt = 0; nt < 2; ++nt) {
    int col = n0 + wn_ * 32 + nt * 16 + l15;
    float bv = bias[col];
    if constexpr (MODE == 2) {
      int h = col >> 6, d = col & 63;
#pragma unroll
      for (int mt = 0; mt < 4; ++mt) {
        int row = m0 + wm_ * 64 + mt * 16 + quad * 4;   // 4 consecutive k (r=0..3)
        int b = row >> 11, k = row & 2047;
        union { ushort_t u[4]; uint2 v; } pk;
#pragma unroll
        for (int r = 0; r < 4; ++r) pk.u[r] = f2b(acc[mt][nt][r] + bv);
        *(uint2*)&((ushort_t*)Cv)[((((size_t)(b * HEADS + h)) * HD + d) << 11) + k] = pk.v;
      }
    } else {
#pragma unroll
      for (int mt = 0; mt < 4; ++mt) {
#pragma unroll
        for (int r = 0; r < 4; ++r) {
          int rowm = m0 + wm_ * 64 + mt * 16 + quad * 4 + r;   // C/D: col=l&15, row=quad*4+r
          float val = (acc[mt][nt][r] + bv) * scale;
          if constexpr (MODE == 0)
            ((ushort_t*)Cv)[rowm * E_DIM + col] = f2b(val);
          else
            ((float*)Cv)[rowm * E_DIM + col] = val;
        }
      }
    }
  }
}

// Fused projections (R3/R8 schedule). Grid = 512*nz blocks, XCD-bijective chunking.
// z = zbase + work/512:  0: qp=(qn@WTq+bq)*QSCALE   1: Vt=T(kvn@WTv+bv)   2: kp=kvn@WTk+bk
__launch_bounds__(256)
__global__ void proj3_kernel(const ushort_t* __restrict__ qn, const ushort_t* __restrict__ WTq,
                             const float* __restrict__ bq, ushort_t* __restrict__ qp,
                             const ushort_t* __restrict__ kvn, const ushort_t* __restrict__ WTv,
                             const float* __restrict__ bv, ushort_t* __restrict__ Vt,
                             const ushort_t* __restrict__ WTk, const float* __restrict__ bk,
                             ushort_t* __restrict__ kp, int zbase) {
  __shared__ ushort_t lA[2 * 128 * 64];
  __shared__ ushort_t lB[2 * 64 * 64];
  int flat = blockIdx.x;
  int chunk = gridDim.x >> 3;
  int work = (flat & 7) * chunk + (flat >> 3);
  int z = zbase + (work >> 9);
  int r = work & 511;
  int m0 = (r >> 3) * 128, n0 = (r & 7) * 64;
  if (z == 0)      gemm_core64<0>(lA, lB, qn,  WTq, bq, qp, QSCALE, m0, n0);
  else if (z == 1) gemm_core64<2>(lA, lB, kvn, WTv, bv, Vt, 1.f,    m0, n0);
  else             gemm_core64<0>(lA, lB, kvn, WTk, bk, kp, 1.f,    m0, n0);
}

// Output GEMM: ctx@WTo+bo -> fp32. 512 blocks, XCD-chunked.
__launch_bounds__(256)
__global__ void out_kernel(const ushort_t* __restrict__ A, const ushort_t* __restrict__ WT,
                           const float* __restrict__ bias, float* __restrict__ C) {
  __shared__ ushort_t lA[2 * 128 * 64];
  __shared__ ushort_t lB[2 * 64 * 64];
  int flat = blockIdx.x;
  int work = (flat & 7) * 64 + (flat >> 3);
  int m0 = (work >> 3) * 128, n0 = (work & 7) * 64;
  gemm_core64<1>(lA, lB, A, WT, bias, C, 1.f, m0, n0);
}

// softmax + in-register P->B-fragment build for one 64-k tile (two 32x32 halves).
// Mask bit order: element (kt2,half,g,r) -> bit (8*kt2+2*g+half)+16*(r&1) of (r<2?lo:hi).
static __device__ __forceinline__ void softmax_frag(const f32x16& s0, const f32x16& s1,
                                                    unsigned mlo, unsigned mhi, int half,
                                                    bf16x8* pf, f32x16* dummy_unused) {
#pragma unroll
  for (int kt2 = 0; kt2 < 2; ++kt2) {
    const f32x16& sv = kt2 ? s1 : s0;
    unsigned wa[4], wb[4];
#pragma unroll
    for (int g = 0; g < 4; ++g) {
      int bb = 8 * kt2 + 2 * g + half;
      unsigned q0u = __float_as_uint(fexp2(sv[g * 4 + 0])) & bitmask1(mlo, bb);
      unsigned q1u = __float_as_uint(fexp2(sv[g * 4 + 1])) & bitmask1(mlo, bb + 16);
      unsigned q2u = __float_as_uint(fexp2(sv[g * 4 + 2])) & bitmask1(mhi, bb);
      unsigned q3u = __float_as_uint(fexp2(sv[g * 4 + 3])) & bitmask1(mhi, bb + 16);
      wa[g] = cvt_pk_bf16(__uint_as_float(q0u), __uint_as_float(q1u));
      wb[g] = cvt_pk_bf16(__uint_as_float(q2u), __uint_as_float(q3u));
    }
    asm("v_permlane32_swap_b32 %0, %1" : "+v"(wa[0]), "+v"(wa[1]));
    asm("v_permlane32_swap_b32 %0, %1" : "+v"(wb[0]), "+v"(wb[1]));
    asm("v_permlane32_swap_b32 %0, %1" : "+v"(wa[2]), "+v"(wa[3]));
    asm("v_permlane32_swap_b32 %0, %1" : "+v"(wb[2]), "+v"(wb[3]));
    union { unsigned u[4]; bf16x8 v; } f0, f1;
    f0.u[0] = wa[0]; f0.u[1] = wb[0]; f0.u[2] = wa[1]; f0.u[3] = wb[1];
    f1.u[0] = wa[2]; f1.u[1] = wb[2]; f1.u[2] = wa[3]; f1.u[3] = wb[3];
    pf[kt2 * 2 + 0] = f0.v;
    pf[kt2 * 2 + 1] = f1.v;
  }
}

// ---------------- flash attention: 2-tile ILP build (R8 — best measured, CONTROL) ----------
// ILP-NOT-OCCUPANCY: R1/R6/R7 proved occupancy is register-capped (~2-3 waves/SIMD, unified
// VGPR+AGPR); latency-hiding comes from TWO independent k-tiles (A,B) per iteration —
// QK/SM/PV chains interleave, barriers per tile halve. 256 threads = (2 q-waves) x
// (2 k-slices); slice ks handles kt = 4*t8 + 2*ks + {0,1}. Partials additive (no-max log2
// softmax) -> 2-way LDS merge. LDS 72KB. XCD-bijective swizzle keeps (b,h) K/V on one XCD L2.
// LDS staging kept: it is the coalescing engine (R5: direct-global = 2.4x slower).
__launch_bounds__(256)
__global__ void attn_kernel(const ushort_t* __restrict__ Qp, const ushort_t* __restrict__ Kp,
                            const ushort_t* __restrict__ Vt,
                            const unsigned long long* __restrict__ bits,
                            ushort_t* __restrict__ ctx) {
  __shared__ __align__(16) char smemb[73728];
  ushort_t* sQ = (ushort_t*)smemb;                        // [0, 8192) — never reused in loop
  int t = threadIdx.x, w = t >> 6, l = t & 63;
  int qw = w & 1, ks = w >> 1;                            // ks in {0,1}
  ushort_t* sKA = (ushort_t*)(smemb + 8192 + ks * 16384); // [8192, 40960)
  ushort_t* sKB = sKA + 4096;
  ushort_t* sVA = (ushort_t*)(smemb + 40960 + ks * 16384);// [40960, 73728)
  ushort_t* sVB = sVA + 4096;
  int l31 = l & 31, half = l >> 5;

  int flat = blockIdx.x;
  int work = (flat & 7) * 128 + (flat >> 3);   // bijective XCD chunking (1024 = 8*128)
  int qblk = work & 31;
  int h = (work >> 5) & 7;
  int b = work >> 8;
  int q0 = qblk * 64;
  int bh = b * HEADS + h;
  int myq = qw * 32 + l31;
  int csrc = ((l & 7) ^ (l >> 3)) * 8;
  int rln = l >> 3;

  // prologue: stage Q (64 rows, 8 DMAs across 4 waves), drain, read loop-invariant frags
#pragma unroll
  for (int it = 0; it < 2; ++it) {
    int r0 = w * 16 + it * 8;
    gl2lds16(&Qp[(size_t)(b * SEQ + q0 + r0 + rln) * E_DIM + h * HD + csrc], &sQ[r0 * 64]);
  }
  __syncthreads();
  bf16x8 qf[4];
#pragma unroll
  for (int ds = 0; ds < 4; ++ds)
    qf[ds] = *(const bf16x8*)&sQ[swz(myq, ds * 16 + 8 * half)];

  const unsigned long long* mrow = bits + ((size_t)(b * SEQ + q0 + myq) << 5);
  f32x16 o0 = {}, o1 = {}, lacc = {};
  union { unsigned u[4]; bf16x8 v; } onec;
#pragma unroll
  for (int i = 0; i < 4; ++i) onec.u[i] = 0x3f803f80u;   // bf16 1.0 pairs

  for (int t8 = 0; t8 < 8; ++t8) {
    int ktA = t8 * 4 + ks * 2;
    int kA0 = ktA * 64, kB0 = kA0 + 64;
    unsigned long long mA = mrow[ktA], mB = mrow[ktA + 1];
    __syncthreads();   // prev iteration's sK/sV reads done (both slices)
    // stage tiles A and B for this slice (2 waves x 16 DMAs)
#pragma unroll
    for (int it = 0; it < 4; ++it) {
      int r0 = (it * 2 + qw) * 8;
      gl2lds16(&Kp[(size_t)(b * SEQ + kA0 + r0 + rln) * E_DIM + h * HD + csrc], &sKA[r0 * 64]);
      gl2lds16(&Kp[(size_t)(b * SEQ + kB0 + r0 + rln) * E_DIM + h * HD + csrc], &sKB[r0 * 64]);
      gl2lds16(&Vt[((size_t)bh * HD + r0 + rln) * SEQ + kA0 + csrc], &sVA[r0 * 64]);
      gl2lds16(&Vt[((size_t)bh * HD + r0 + rln) * SEQ + kB0 + csrc], &sVB[r0 * 64]);
    }
    __syncthreads();   // DMA drained

    // QK^T for both tiles — independent chains, compiler interleaves
    f32x16 sA0 = {}, sA1 = {}, sB0 = {}, sB1 = {};
    __builtin_amdgcn_s_setprio(1);
#pragma unroll
    for (int ds = 0; ds < 4; ++ds) {
      bf16x8 kfA0 = *(const bf16x8*)&sKA[swz(l31, ds * 16 + 8 * half)];
      bf16x8 kfA1 = *(const bf16x8*)&sKA[swz(32 + l31, ds * 16 + 8 * half)];
      bf16x8 kfB0 = *(const bf16x8*)&sKB[swz(l31, ds * 16 + 8 * half)];
      bf16x8 kfB1 = *(const bf16x8*)&sKB[swz(32 + l31, ds * 16 + 8 * half)];
      sA0 = __builtin_amdgcn_mfma_f32_32x32x16_bf16(kfA0, qf[ds], sA0, 0, 0, 0);
      sA1 = __builtin_amdgcn_mfma_f32_32x32x16_bf16(kfA1, qf[ds], sA1, 0, 0, 0);
      sB0 = __builtin_amdgcn_mfma_f32_32x32x16_bf16(kfB0, qf[ds], sB0, 0, 0, 0);
      sB1 = __builtin_amdgcn_mfma_f32_32x32x16_bf16(kfB1, qf[ds], sB1, 0, 0, 0);
    }
    __builtin_amdgcn_s_setprio(0);

    // softmax for both tiles (independent VALU chains)
    bf16x8 pfA[4], pfB[4];
    softmax_frag(sA0, sA1, (unsigned)mA, (unsigned)(mA >> 32), half, pfA, nullptr);
    softmax_frag(sB0, sB1, (unsigned)mB, (unsigned)(mB >> 32), half, pfB, nullptr);

    // O^T += V^T P^T for both tiles ; lacc += 1^T P^T (row-sums on the MFMA pipe)
    __builtin_amdgcn_s_setprio(1);
#pragma unroll
    for (int ksp = 0; ksp < 4; ++ksp) {
      bf16x8 vfA0 = *(const bf16x8*)&sVA[swz(l31, ksp * 16 + 8 * half)];
      bf16x8 vfA1 = *(const bf16x8*)&sVA[swz(32 + l31, ksp * 16 + 8 * half)];
      o0 = __builtin_amdgcn_mfma_f32_32x32x16_bf16(vfA0, pfA[ksp], o0, 0, 0, 0);
      o1 = __builtin_amdgcn_mfma_f32_32x32x16_bf16(vfA1, pfA[ksp], o1, 0, 0, 0);
      lacc = __builtin_amdgcn_mfma_f32_32x32x16_bf16(onec.v, pfA[ksp], lacc, 0, 0, 0);
      bf16x8 vfB0 = *(const bf16x8*)&sVB[swz(l31, ksp * 16 + 8 * half)];
      bf16x8 vfB1 = *(const bf16x8*)&sVB[swz(32 + l31, ksp * 16 + 8 * half)];
      o0 = __builtin_amdgcn_mfma_f32_32x32x16_bf16(vfB0, pfB[ksp], o0, 0, 0, 0);
      o1 = __builtin_amdgcn_mfma_f32_32x32x16_bf16(vfB1, pfB[ksp], o1, 0, 0, 0);
      lacc = __builtin_amdgcn_mfma_f32_32x32x16_bf16(onec.v, pfB[ksp], lacc, 0, 0, 0);
    }
    __builtin_amdgcn_s_setprio(0);
  }

  // lacc[0] = full slice row-sum for q=lane&31 (identical in both halves)
  float lsum = lacc[0];

  // cross-slice merge: slice 1 writes partials to LDS (K area dead), slice 0 adds.
  __syncthreads();                       // all compute done before overwriting K area
  float* mrg = (float*)(smemb + 8192);   // [2 qw][64 lanes][33 floats] = 16.9KB
  if (ks == 1) {
    float* e = mrg + (qw * 64 + l) * 33;
#pragma unroll
    for (int r = 0; r < 16; ++r) e[r] = o0[r];
#pragma unroll
    for (int r = 0; r < 16; ++r) e[16 + r] = o1[r];
    e[32] = lsum;
  }
  __syncthreads();
  if (ks == 0) {
    const float* e = mrg + (qw * 64 + l) * 33;
#pragma unroll
    for (int r = 0; r < 16; ++r) o0[r] += e[r];
#pragma unroll
    for (int r = 0; r < 16; ++r) o1[r] += e[16 + r];
    lsum += e[32];
    float inv = (lsum > 0.f) ? 1.f / lsum : 0.f;   // all-masked row -> 0 (nan_to_num)
    size_t base = (size_t)(b * SEQ + q0 + myq) * E_DIM + h * HD;
#pragma unroll
    for (int dt = 0; dt < 2; ++dt) {
      const f32x16& oo = dt ? o1 : o0;
#pragma unroll
      for (int g = 0; g < 4; ++g) {
        union { ushort_t u[4]; uint2 v; } ov;
#pragma unroll
        for (int r = 0; r < 4; ++r) ov.u[r] = f2b(oo[g * 4 + r] * inv);
        *(uint2*)&ctx[base + dt * 32 + g * 8 + 4 * half] = ov.v;   // d=(r)+8g+4*half+32dt
      }
    }
  }
}

// ---------------- launch (R8 schedule) ----------------
// fp32 in/out, bf16 internals. d_out (16 MB fp32) = two 8 MB bf16 slots dlo/dhi.
// Preferred (ws >= 28 MiB): bufA(8) bufB(8) WT(2) bits(2) bufC(8):
//   1 prep:  WT, bits, qn->dlo, kvn->bufA                 (7168 blocks)
//   2 proj3: qp->dhi, Vt->bufB, kp->bufC                  (1536 blocks)
//   3 attn:  (dhi, bufC, bufB, bits) -> bufA              (1024 x 256)
//   4 out:   bufA@WTo+bo -> d_out fp32                    (512)
// Fallback (ws < 28 MiB): proj3 split into (q,v) then (k->dlo).
extern "C" void kernel_launch(void* const* d_in, const int* in_sizes, int n_in,
                              void* d_out, int out_size, void* d_ws, size_t ws_size,
                              hipStream_t stream) {
  const float* query     = (const float*)d_in[0];
  const float* key_value = (const float*)d_in[1];
  const int*   kv_mask   = (const int*)d_in[2];
  const int*   sp_mask   = (const int*)d_in[3];
  const float* ln_q_g  = (const float*)d_in[4];
  const float* ln_q_b  = (const float*)d_in[5];
  const float* ln_kv_g = (const float*)d_in[6];
  const float* ln_kv_b = (const float*)d_in[7];
  const float* Wq = (const float*)d_in[8];
  const float* bq = (const float*)d_in[9];
  const float* Wk = (const float*)d_in[10];
  const float* bk = (const float*)d_in[11];
  const float* Wv = (const float*)d_in[12];
  const float* bv = (const float*)d_in[13];
  const float* Wo = (const float*)d_in[14];
  const float* bo = (const float*)d_in[15];

  const size_t NB = (size_t)NROWS * E_DIM;       // 8 MiB bf16 slot
  char* ws = (char*)d_ws;
  ushort_t* bufA = (ushort_t*)ws;                // kvn -> ctx
  ushort_t* bufB = bufA + NB;                    // Vt
  ushort_t* WT   = bufB + NB;                    // 4 x 512x512 bf16 = 2 MiB
  ushort_t* WTq = WT;
  ushort_t* WTk = WTq + E_DIM * E_DIM;
  ushort_t* WTv = WTk + E_DIM * E_DIM;
  ushort_t* WTo = WTv + E_DIM * E_DIM;
  unsigned long long* bits = (unsigned long long*)(WTo + E_DIM * E_DIM);  // 2 MiB
  ushort_t* bufC = (ushort_t*)(ws + (20u << 20));                         // kp (8 MiB)

  ushort_t* dlo = (ushort_t*)d_out;              // qn, then (fallback) kp
  ushort_t* dhi = dlo + NB;                      // qp

  bool fused = ws_size >= (28u << 20);
  ushort_t* kp = fused ? bufC : dlo;

  prep_kernel<<<7168, 256, 0, stream>>>(Wq, Wk, Wv, Wo, WT, kv_mask, sp_mask, bits,
                                        query, key_value, ln_q_g, ln_q_b, ln_kv_g, ln_kv_b,
                                        dlo, bufA);

  if (fused) {
    proj3_kernel<<<1536, 256, 0, stream>>>(dlo, WTq, bq, dhi,
                                           bufA, WTv, bv, bufB,
                                           WTk, bk, bufC, 0);
  } else {
    proj3_kernel<<<1024, 256, 0, stream>>>(dlo, WTq, bq, dhi,
                                           bufA, WTv, bv, bufB,
                                           WTk, bk, dlo, 0);       // z in {0,1}: kp unused
    proj3_kernel<<<512, 256, 0, stream>>>(dlo, WTq, bq, dhi,
                                          bufA, WTv, bv, bufB,
                                          WTk, bk, dlo, 2);        // z = 2: kp -> dlo
  }

  attn_kernel<<<1024, 256, 0, stream>>>(dhi, kp, bufB, bits, bufA);

  out_kernel<<<512, 256, 0, stream>>>(bufA, WTo, bo, (float*)d_out);
}